// Round 9
// baseline (341.552 us; speedup 1.0000x reference)
//
#include <hip/hip_runtime.h>

// IrisSpecializedLoss — round-9: ONE fused streaming kernel (+ rules + final).
// r8 evidence: all my kernels < 85 µs (dropped out of top-5 behind harness
// 0xAA fills @6.9 TB/s), but total kernel time ≈ 125 µs — the decomposition
// re-read att (flat sweep + gathers) and targets. Fix: single quad-based
// kernel touching each input byte exactly ONCE, all loads >=128-bit:
//   per quad: int4 targets; 10x float4 logits -> ONLINE softmax/argmax
//   (live set ~20 regs, no resident x[10][4] => no spill — r2's killer);
//   10x float4 att -> sum(a^2) and cndmask-select of a_t (gather-free).
// colormap identity: sum(a-onehot)^2 = sum(a^2) - 2*sum(a_t) + #pixels.
// consistency: border-weighted eq sum (integer-exact).
// Grid 1800x256, exactly 2 quads/thread (no tail). Rules kernel re-reads
// targets (L3-warm, 14.7 MB) per batch; deterministic double finalize.

namespace {
constexpr int kB = 4096;
constexpr int kC = 10;
constexpr int kH = 30;
constexpr int kW = 30;
constexpr int kHW = kH * kW;              // 900
constexpr int kCHW = kC * kHW;            // 9000
constexpr int kQuadsPerB = kHW / 4;       // 225
constexpr int kQuads = kB * kQuadsPerB;   // 921600
constexpr int kThreads = 256;
constexpr int kGrid = 1800;               // ~7 blocks/CU
constexpr int kQPT = 2;                   // quads per thread, exact
static_assert(kGrid * kThreads * kQPT == kQuads, "work split must be exact");
}  // namespace

// ---------- K-fused: CE + argmax + consistency + colormap ----------
__global__ __launch_bounds__(kThreads) void iris_fused(
    const float* __restrict__ logits_g,   // [B,C,H,W]
    const int* __restrict__ targets_g,    // [B,H,W]
    const float* __restrict__ att_g,      // [B,H,W,C]
    float* __restrict__ ce_part,          // [kGrid]
    float* __restrict__ cmat_part,        // [kGrid] sum a_t
    float* __restrict__ cmsq_part,        // [kGrid] sum a^2
    unsigned* __restrict__ weq_part,      // [kGrid]
    unsigned* __restrict__ eq_part)       // [kGrid]
{
    const int tid = threadIdx.x;
    const int gid = blockIdx.x * kThreads + tid;

    float ce_acc = 0.f, at_acc = 0.f, sq_acc = 0.f;
    unsigned weq_acc = 0u, eq_acc = 0u;

#pragma unroll
    for (int k = 0; k < kQPT; ++k) {
        const int q = gid + k * (kGrid * kThreads);
        const int b = q / kQuadsPerB;             // const-div -> magic mul
        const int i = q - b * kQuadsPerB;
        const int p0 = 4 * i;

        // ---- targets: one coalesced int4 ----
        const int4 tv = *reinterpret_cast<const int4*>(targets_g + (size_t)b * kHW + p0);
        const int ta[4] = {tv.x, tv.y, tv.z, tv.w};

        // ---- att: 10 contiguous float4 (160B); online sq + a_t select ----
        const float* __restrict__ ap = att_g + (size_t)b * kCHW + (size_t)p0 * kC;
        float atq[4] = {0.f, 0.f, 0.f, 0.f};
#pragma unroll
        for (int u = 0; u < kC; ++u) {
            const float4 v = *reinterpret_cast<const float4*>(ap + 4 * u);
            const float av[4] = {v.x, v.y, v.z, v.w};
#pragma unroll
            for (int e2 = 0; e2 < 4; ++e2) {
                const int e = 4 * u + e2;     // 0..39, compile-time
                const int j = e / kC;         // owning pixel in quad
                const int ch = e - j * kC;    // channel
                sq_acc += av[e2] * av[e2];
                atq[j] = (ch == ta[j]) ? av[e2] : atq[j];   // cndmask
            }
        }
        at_acc += atq[0] + atq[1] + atq[2] + atq[3];

        // ---- logits: 10 channel-plane float4, ONLINE softmax + argmax ----
        const float* __restrict__ lg = logits_g + (size_t)b * kCHW + p0;
        float m[4], s[4], xt[4];
        int am[4];
#pragma unroll
        for (int j = 0; j < 4; ++j) { m[j] = -3.4e38f; s[j] = 0.f; xt[j] = 0.f; am[j] = 0; }
#pragma unroll
        for (int c = 0; c < kC; ++c) {
            const float4 v = *reinterpret_cast<const float4*>(lg + c * kHW);
            const float xv[4] = {v.x, v.y, v.z, v.w};
#pragma unroll
            for (int j = 0; j < 4; ++j) {
                const bool gt = xv[j] > m[j];          // strict >: first max (JAX)
                const float mn = gt ? xv[j] : m[j];
                // c==0: s=0, exp(-3.4e38-x) flushes to 0 -> s=1 correctly
                s[j] = s[j] * __expf(m[j] - mn) + __expf(xv[j] - mn);
                m[j] = mn;
                am[j] = gt ? c : am[j];
                xt[j] = (c == ta[j]) ? xv[j] : xt[j];  // compile-time c -> cndmask
            }
        }
#pragma unroll
        for (int j = 0; j < 4; ++j) {
            ce_acc += m[j] + __logf(s[j]) - xt[j];
            const unsigned eq = (am[j] == ta[j]) ? 1u : 0u;
            eq_acc += eq;
            const int p = p0 + j;
            const int h = p / kW;
            const int w = p - h * kW;
            weq_acc += eq * (((h == 0 || h == kH - 1) ? 1u : 2u) *
                             ((w == 0 || w == kW - 1) ? 1u : 2u));
        }
    }

    // ---- wave + block reduce ----
#pragma unroll
    for (int off = 32; off > 0; off >>= 1) {
        ce_acc  += __shfl_down(ce_acc, off);
        at_acc  += __shfl_down(at_acc, off);
        sq_acc  += __shfl_down(sq_acc, off);
        weq_acc += __shfl_down(weq_acc, off);
        eq_acc  += __shfl_down(eq_acc, off);
    }
    __shared__ float sf[3][4];
    __shared__ unsigned su[2][4];
    const int wave = tid >> 6;
    if ((tid & 63) == 0) {
        sf[0][wave] = ce_acc; sf[1][wave] = at_acc; sf[2][wave] = sq_acc;
        su[0][wave] = weq_acc; su[1][wave] = eq_acc;
    }
    __syncthreads();
    if (tid == 0) {
        ce_part[blockIdx.x]   = sf[0][0] + sf[0][1] + sf[0][2] + sf[0][3];
        cmat_part[blockIdx.x] = sf[1][0] + sf[1][1] + sf[1][2] + sf[1][3];
        cmsq_part[blockIdx.x] = sf[2][0] + sf[2][1] + sf[2][2] + sf[2][3];
        weq_part[blockIdx.x]  = su[0][0] + su[0][1] + su[0][2] + su[0][3];
        eq_part[blockIdx.x]   = su[1][0] + su[1][1] + su[1][2] + su[1][3];
    }
}

// ---------- K-rules: one wave per batch (targets L3-warm re-read) ----------
__global__ __launch_bounds__(64) void iris_rules(
    const int* __restrict__ targets_g, const float* __restrict__ rules_g,
    float* __restrict__ rule_part) {
    const int b = blockIdx.x;
    const int lane = threadIdx.x;
    const int* __restrict__ tgt = targets_g + (size_t)b * kHW;
    unsigned mask = 0u;
    for (int k = lane; k < kHW; k += 64) mask |= 1u << tgt[k];  // coalesced
#pragma unroll
    for (int off = 32; off > 0; off >>= 1) mask |= __shfl_down(mask, off);
    if (lane == 0) {
        const float* __restrict__ lr = rules_g + (size_t)b * kC;
        unsigned mrem = mask;
        float rl = 0.f;
#pragma unroll
        for (int s2 = 0; s2 < kC; ++s2) {
            float v = 0.f;
            if (mrem) {
                v = (float)(__ffs(mrem) - 1);   // s-th smallest present color
                mrem &= mrem - 1u;
            }
            const float d = lr[s2] - v;
            rl += d * d;
        }
        rule_part[b] = rl;
    }
}

// ---------- K-final: deterministic double reduce ----------
__global__ __launch_bounds__(1024) void iris_finalize(
    const float* __restrict__ ce_part,
    const float* __restrict__ cmat_part,
    const float* __restrict__ cmsq_part,
    const unsigned* __restrict__ weq_part,
    const unsigned* __restrict__ eq_part,
    const float* __restrict__ rule_part,
    float* __restrict__ out) {
    const int tid = threadIdx.x;
    double ce = 0.0, cma = 0.0, cms = 0.0, rl = 0.0;
    unsigned long long weq = 0ull, eqc = 0ull;
    for (int i = tid; i < kGrid; i += 1024) {    // kGrid=1800: bounded loop
        ce  += (double)ce_part[i];
        cma += (double)cmat_part[i];
        cms += (double)cmsq_part[i];
        weq += (unsigned long long)weq_part[i];
        eqc += (unsigned long long)eq_part[i];
    }
#pragma unroll
    for (int k = 0; k < 4; ++k) rl += (double)rule_part[tid + 1024 * k];
#pragma unroll
    for (int off = 32; off > 0; off >>= 1) {
        ce  += __shfl_down(ce, off);
        cma += __shfl_down(cma, off);
        cms += __shfl_down(cms, off);
        rl  += __shfl_down(rl, off);
        weq += __shfl_down(weq, off);
        eqc += __shfl_down(eqc, off);
    }
    __shared__ double sd[4][16];
    __shared__ unsigned long long su[2][16];
    const int wave = tid >> 6;
    if ((tid & 63) == 0) {
        sd[0][wave] = ce; sd[1][wave] = cma; sd[2][wave] = cms; sd[3][wave] = rl;
        su[0][wave] = weq; su[1][wave] = eqc;
    }
    __syncthreads();
    if (tid == 0) {
        ce = 0.0; cma = 0.0; cms = 0.0; rl = 0.0; weq = 0ull; eqc = 0ull;
#pragma unroll
        for (int i = 0; i < 16; ++i) {
            ce += sd[0][i]; cma += sd[1][i]; cms += sd[2][i]; rl += sd[3][i];
            weq += su[0][i]; eqc += su[1][i];
        }
        const double npix = (double)kB * kHW;
        const double ce_m = ce / npix;
        const double cm_m = (cms - 2.0 * cma + npix) / (npix * kC);
        const double s_mean = (double)weq / ((double)kB * (kH - 1) * (kW - 1));
        const double cons = 1.0 - s_mean / 4.0;
        const double rl_m = rl / ((double)kB * kC);
        const double exact = (double)eqc;
        double total = ce_m + 0.4 * cm_m + 0.3 * cons + 0.2 * rl_m
                       - (exact / (double)kB) * 5.0;
        if (total < 0.001) total = 0.001;
        out[0] = (float)total;
        out[1] = (float)ce_m;
        out[2] = (float)cm_m;
        out[3] = (float)cons;
        out[4] = (float)rl_m;
        out[5] = (float)exact;
    }
}

extern "C" void kernel_launch(void* const* d_in, const int* in_sizes, int n_in,
                              void* d_out, int out_size, void* d_ws, size_t ws_size,
                              hipStream_t stream) {
    const float* color_output    = (const float*)d_in[0];
    const int*   targets         = (const int*)d_in[1];
    const float* color_attention = (const float*)d_in[2];
    const float* lstm_rules      = (const float*)d_in[3];
    float* out = (float*)d_out;

    // workspace: 5 x kGrid + kB rules  (~52 KB)
    float*    ce_part   = (float*)d_ws;
    float*    cmat_part = ce_part + kGrid;
    float*    cmsq_part = cmat_part + kGrid;
    unsigned* weq_part  = (unsigned*)(cmsq_part + kGrid);
    unsigned* eq_part   = weq_part + kGrid;
    float*    rule_part = (float*)(eq_part + kGrid);

    iris_fused<<<kGrid, kThreads, 0, stream>>>(color_output, targets, color_attention,
                                               ce_part, cmat_part, cmsq_part,
                                               weq_part, eq_part);
    iris_rules<<<kB, 64, 0, stream>>>(targets, lstm_rules, rule_part);
    iris_finalize<<<1, 1024, 0, stream>>>(ce_part, cmat_part, cmsq_part,
                                          weq_part, eq_part, rule_part, out);
}

// Round 11
// 330.730 us; speedup vs baseline: 1.0327x; 1.0327x over previous
//
#include <hip/hip_runtime.h>

// IrisSpecializedLoss — round-11: max-TLP fully-coalesced fused kernel.
// Measured history: r2/r5/r7/r9 = 115/110/114/127 µs (~2.5 TB/s) across reg-
// resident, fence-clustered, LDS-staged, and quad-fused structures — while
// the harness fill hits 6.9 TB/s at 9.5% occupancy in the SAME captures.
// r5/r7 refute pure load-serialization; r9 had 160B-stride att loads and 53%
// occupancy. This round mimics the proven-fast pattern exactly:
//   * EVERY global instruction lane-contiguous (consecutive lanes ->
//     consecutive addresses): att 5x float4/thread, targets 1 dword/px,
//     logits 10 dwords/px (consecutive pixels across lanes).
//   * 100% occupancy: LDS exactly 20480B -> 8 blocks/CU -> 32 waves/CU;
//     ~35 VGPR live set -> no allocator pressure, no spill.
//   * a_t via LDS redistribution (runtime LDS addressing is fine; runtime
//     REGISTER indexing was r2's spill bug) — att read from HBM exactly once.
// Math (passed absmax=0 in r9): CE two-pass softmax; argmax strict > (JAX
// first-max); border-weighted eq (integer-exact); colormap = sum(a^2)
// - 2*sum(a_t) + #px; rules presence-mask kernel; double finalize.

namespace {
constexpr int kB = 4096;
constexpr int kC = 10;
constexpr int kH = 30;
constexpr int kW = 30;
constexpr int kHW = kH * kW;                 // 900
constexpr int kCHW = kC * kHW;               // 9000
constexpr int kPix = kB * kHW;               // 3686400
constexpr int kThreads = 256;
constexpr int kPPT = 2;                      // pixels per thread
constexpr int kPixPerBlk = kThreads * kPPT;  // 512
constexpr int kGridF = kPix / kPixPerBlk;    // 7200 blocks
static_assert(kGridF * kPixPerBlk == kPix, "exact split");
constexpr int kAttFlt = kPixPerBlk * kC;     // 5120 floats = 20480 B LDS
}  // namespace

typedef float f32x4 __attribute__((ext_vector_type(4)));

// ---------- K-fused: CE + argmax + consistency + colormap ----------
__global__ __launch_bounds__(kThreads) void iris_fused(
    const float* __restrict__ logits_g,   // [B,C,H,W]
    const int* __restrict__ targets_g,    // [B,H,W]
    const float* __restrict__ att_g,      // [B,H,W,C]
    float* __restrict__ ce_part,          // [kGridF]
    float* __restrict__ cmat_part,        // [kGridF] sum a_t
    float* __restrict__ cmsq_part,        // [kGridF] sum a^2
    unsigned* __restrict__ weq_part,      // [kGridF]
    unsigned* __restrict__ eq_part)       // [kGridF]
{
    __shared__ float lds_att[kAttFlt];    // 20480 B; reused as reduce scratch
    const int tid = threadIdx.x;
    const int blk = blockIdx.x;

    // ---- 1. stage block's att slice (20KB) to LDS; sum-sq on the fly.
    //         5 lane-contiguous float4 loads: 1KB/wave-instr, fill-like ----
    const float* __restrict__ ab = att_g + (size_t)blk * kAttFlt;
    float sq_acc = 0.f;
#pragma unroll
    for (int k = 0; k < 5; ++k) {
        const int f4 = tid + kThreads * k;
        const f32x4 v = *reinterpret_cast<const f32x4*>(ab + 4 * f4);
        sq_acc += v[0] * v[0] + v[1] * v[1] + v[2] * v[2] + v[3] * v[3];
        *reinterpret_cast<f32x4*>(lds_att + 4 * f4) = v;
    }

    // ---- 2. per-pixel: targets + logits, all lane-contiguous dwords ----
    float ce_acc = 0.f;
    unsigned weq_acc = 0u, eq_acc = 0u;
    int tsv[kPPT];
#pragma unroll
    for (int u = 0; u < kPPT; ++u) {
        const int p = blk * kPixPerBlk + tid + kThreads * u;  // global pixel
        const int b = p / kHW;            // const-div -> magic mul
        const int i = p - b * kHW;
        const int t = targets_g[p];       // linear in p: perfectly coalesced
        tsv[u] = t;

        const float* __restrict__ lg = logits_g + (size_t)b * kCHW + i;
        float x[kC];
#pragma unroll
        for (int c = 0; c < kC; ++c) x[c] = lg[c * kHW];  // 10 coalesced dwords

        float m = x[0];
        int am = 0;
        float xt = (t == 0) ? x[0] : 0.f;
#pragma unroll
        for (int c = 1; c < kC; ++c) {
            const bool gt = x[c] > m;     // strict >: first max (JAX)
            am = gt ? c : am;
            m = gt ? x[c] : m;
            xt = (c == t) ? x[c] : xt;    // compile-time c -> cndmask
        }
        float s = 0.f;
#pragma unroll
        for (int c = 0; c < kC; ++c) s += __expf(x[c] - m);
        ce_acc += m + __logf(s) - xt;

        const unsigned eq = (am == t) ? 1u : 0u;
        eq_acc += eq;
        const int h = i / kW;
        const int w = i - h * kW;
        weq_acc += eq * (((h == 0 || h == kH - 1) ? 1u : 2u) *
                         ((w == 0 || w == kW - 1) ? 1u : 2u));
    }

    // ---- 3. a_t from LDS (dynamic LDS addressing; ~4-way conflicts max) ----
    __syncthreads();   // staging writes visible
    float at_acc = 0.f;
#pragma unroll
    for (int u = 0; u < kPPT; ++u) {
        const int p_local = tid + kThreads * u;
        at_acc += lds_att[p_local * kC + tsv[u]];
    }

    // ---- 4. wave reduce + cross-wave via reused LDS ----
#pragma unroll
    for (int off = 32; off > 0; off >>= 1) {
        ce_acc  += __shfl_down(ce_acc, off);
        at_acc  += __shfl_down(at_acc, off);
        sq_acc  += __shfl_down(sq_acc, off);
        weq_acc += __shfl_down(weq_acc, off);
        eq_acc  += __shfl_down(eq_acc, off);
    }
    __syncthreads();   // all a_t reads done; safe to reuse lds_att
    float* rf = lds_att;                            // [0..11] floats
    unsigned* ru = reinterpret_cast<unsigned*>(lds_att + 12);  // [12..19]
    const int wave = tid >> 6;
    if ((tid & 63) == 0) {
        rf[wave] = ce_acc;
        rf[4 + wave] = at_acc;
        rf[8 + wave] = sq_acc;
        ru[wave] = weq_acc;
        ru[4 + wave] = eq_acc;
    }
    __syncthreads();
    if (tid == 0) {
        ce_part[blk]   = rf[0] + rf[1] + rf[2] + rf[3];
        cmat_part[blk] = rf[4] + rf[5] + rf[6] + rf[7];
        cmsq_part[blk] = rf[8] + rf[9] + rf[10] + rf[11];
        weq_part[blk]  = ru[0] + ru[1] + ru[2] + ru[3];
        eq_part[blk]   = ru[4] + ru[5] + ru[6] + ru[7];
    }
}

// ---------- K-rules: one wave per batch (targets L3-warm re-read) ----------
__global__ __launch_bounds__(64) void iris_rules(
    const int* __restrict__ targets_g, const float* __restrict__ rules_g,
    float* __restrict__ rule_part) {
    const int b = blockIdx.x;
    const int lane = threadIdx.x;
    const int* __restrict__ tgt = targets_g + (size_t)b * kHW;
    unsigned mask = 0u;
    for (int k = lane; k < kHW; k += 64) mask |= 1u << tgt[k];  // coalesced
#pragma unroll
    for (int off = 32; off > 0; off >>= 1) mask |= __shfl_down(mask, off);
    if (lane == 0) {
        const float* __restrict__ lr = rules_g + (size_t)b * kC;
        unsigned mrem = mask;
        float rl = 0.f;
#pragma unroll
        for (int s2 = 0; s2 < kC; ++s2) {
            float v = 0.f;
            if (mrem) {
                v = (float)(__ffs(mrem) - 1);   // s-th smallest present color
                mrem &= mrem - 1u;
            }
            const float d = lr[s2] - v;
            rl += d * d;
        }
        rule_part[b] = rl;
    }
}

// ---------- K-final: deterministic double reduce ----------
__global__ __launch_bounds__(1024) void iris_finalize(
    const float* __restrict__ ce_part,
    const float* __restrict__ cmat_part,
    const float* __restrict__ cmsq_part,
    const unsigned* __restrict__ weq_part,
    const unsigned* __restrict__ eq_part,
    const float* __restrict__ rule_part,
    float* __restrict__ out) {
    const int tid = threadIdx.x;
    double ce = 0.0, cma = 0.0, cms = 0.0, rl = 0.0;
    unsigned long long weq = 0ull, eqc = 0ull;
    for (int i = tid; i < kGridF; i += 1024) {
        ce  += (double)ce_part[i];
        cma += (double)cmat_part[i];
        cms += (double)cmsq_part[i];
        weq += (unsigned long long)weq_part[i];
        eqc += (unsigned long long)eq_part[i];
    }
#pragma unroll
    for (int k = 0; k < 4; ++k) rl += (double)rule_part[tid + 1024 * k];
#pragma unroll
    for (int off = 32; off > 0; off >>= 1) {
        ce  += __shfl_down(ce, off);
        cma += __shfl_down(cma, off);
        cms += __shfl_down(cms, off);
        rl  += __shfl_down(rl, off);
        weq += __shfl_down(weq, off);
        eqc += __shfl_down(eqc, off);
    }
    __shared__ double sd[4][16];
    __shared__ unsigned long long su[2][16];
    const int wave = tid >> 6;
    if ((tid & 63) == 0) {
        sd[0][wave] = ce; sd[1][wave] = cma; sd[2][wave] = cms; sd[3][wave] = rl;
        su[0][wave] = weq; su[1][wave] = eqc;
    }
    __syncthreads();
    if (tid == 0) {
        ce = 0.0; cma = 0.0; cms = 0.0; rl = 0.0; weq = 0ull; eqc = 0ull;
#pragma unroll
        for (int i = 0; i < 16; ++i) {
            ce += sd[0][i]; cma += sd[1][i]; cms += sd[2][i]; rl += sd[3][i];
            weq += su[0][i]; eqc += su[1][i];
        }
        const double npix = (double)kB * kHW;
        const double ce_m = ce / npix;
        const double cm_m = (cms - 2.0 * cma + npix) / (npix * kC);
        const double s_mean = (double)weq / ((double)kB * (kH - 1) * (kW - 1));
        const double cons = 1.0 - s_mean / 4.0;
        const double rl_m = rl / ((double)kB * kC);
        const double exact = (double)eqc;
        double total = ce_m + 0.4 * cm_m + 0.3 * cons + 0.2 * rl_m
                       - (exact / (double)kB) * 5.0;
        if (total < 0.001) total = 0.001;
        out[0] = (float)total;
        out[1] = (float)ce_m;
        out[2] = (float)cm_m;
        out[3] = (float)cons;
        out[4] = (float)rl_m;
        out[5] = (float)exact;
    }
}

extern "C" void kernel_launch(void* const* d_in, const int* in_sizes, int n_in,
                              void* d_out, int out_size, void* d_ws, size_t ws_size,
                              hipStream_t stream) {
    const float* color_output    = (const float*)d_in[0];
    const int*   targets         = (const int*)d_in[1];
    const float* color_attention = (const float*)d_in[2];
    const float* lstm_rules      = (const float*)d_in[3];
    float* out = (float*)d_out;

    // workspace: 5 x kGridF + kB rules = 160,384 B
    float*    ce_part   = (float*)d_ws;
    float*    cmat_part = ce_part + kGridF;
    float*    cmsq_part = cmat_part + kGridF;
    unsigned* weq_part  = (unsigned*)(cmsq_part + kGridF);
    unsigned* eq_part   = weq_part + kGridF;
    float*    rule_part = (float*)(eq_part + kGridF);

    iris_fused<<<kGridF, kThreads, 0, stream>>>(color_output, targets,
                                                color_attention, ce_part,
                                                cmat_part, cmsq_part,
                                                weq_part, eq_part);
    iris_rules<<<kB, 64, 0, stream>>>(targets, lstm_rules, rule_part);
    iris_finalize<<<1, 1024, 0, stream>>>(ce_part, cmat_part, cmsq_part,
                                          weq_part, eq_part, rule_part, out);
}

// Round 12
// 328.364 us; speedup vs baseline: 1.0402x; 1.0072x over previous
//
#include <hip/hip_runtime.h>

// IrisSpecializedLoss — round-12: forced load-batching (r10 design, never
// ran: GPU timeout), simplified to 1 quad/thread.
// Evidence r2/r5/r7/r9/r11: six structures, 110-127 µs (~2.8 TB/s read),
// VGPR 24-52 every time. r11 (perfect coalescing, 75% occ, VGPR=24) kills
// the occupancy/coalescing theories. Little's law at 2.77 TB/s & ~700ns:
// ~1.2 outstanding loads/wave — the allocator's tiny register budget
// windows 21 independent loads into a serial vmcnt chain. Only untested
// fix: FORCE all 21 results live via asm "+v" fence (cannot sink, cannot
// window). Discriminates MLP-starvation vs a ~3 TB/s read-path cap
// (fill=6.9 TB/s write-only; m13 copy=3.15 TB/s read-side).
//   per quad: int4 targets + 10 att f32x4 + 10 logits f32x4 -> fence ->
//   sum a^2 / a_t select; two-pass softmax+argmax on resident regs.
// Math identical to r9/r11 (passed, absmax=0): CE = m+log(sum exp(x-m))-x_t;
// argmax strict > (JAX first-max); border-weighted eq (integer-exact);
// colormap = sum(a^2)-2*sum(a_t)+#px; rules presence-mask; double finalize.

namespace {
constexpr int kB = 4096;
constexpr int kC = 10;
constexpr int kH = 30;
constexpr int kW = 30;
constexpr int kHW = kH * kW;              // 900
constexpr int kCHW = kC * kHW;            // 9000
constexpr int kQuadsPerB = kHW / 4;       // 225
constexpr int kQuads = kB * kQuadsPerB;   // 921600
constexpr int kThreads = 256;
constexpr int kGrid = kQuads / kThreads;  // 3600 blocks, 1 quad/thread
static_assert(kGrid * kThreads == kQuads, "exact split");
}  // namespace

typedef float f32x4 __attribute__((ext_vector_type(4)));
typedef int i32x4 __attribute__((ext_vector_type(4)));

// ---------- K-fused: CE + argmax + consistency + colormap ----------
__global__ __launch_bounds__(kThreads, 4) void iris_fused(
    const float* __restrict__ logits_g,   // [B,C,H,W]
    const int* __restrict__ targets_g,    // [B,H,W]
    const float* __restrict__ att_g,      // [B,H,W,C]
    float* __restrict__ ce_part,          // [kGrid]
    float* __restrict__ cmat_part,        // [kGrid] sum a_t
    float* __restrict__ cmsq_part,        // [kGrid] sum a^2
    unsigned* __restrict__ weq_part,      // [kGrid]
    unsigned* __restrict__ eq_part)       // [kGrid]
{
    const int tid = threadIdx.x;
    const int q = blockIdx.x * kThreads + tid;   // one quad per thread
    const int b = q / kQuadsPerB;                // const-div -> magic mul
    const int i = q - b * kQuadsPerB;
    const int p0 = 4 * i;

    const float* __restrict__ ap = att_g + (size_t)b * kCHW + (size_t)p0 * kC;
    const float* __restrict__ lg = logits_g + (size_t)b * kCHW + p0;

    // ---- issue ALL 21 loads into named registers ----
    i32x4 tv = *reinterpret_cast<const i32x4*>(targets_g + (size_t)b * kHW + p0);
    f32x4 a0 = *reinterpret_cast<const f32x4*>(ap + 0);
    f32x4 a1 = *reinterpret_cast<const f32x4*>(ap + 4);
    f32x4 a2 = *reinterpret_cast<const f32x4*>(ap + 8);
    f32x4 a3 = *reinterpret_cast<const f32x4*>(ap + 12);
    f32x4 a4 = *reinterpret_cast<const f32x4*>(ap + 16);
    f32x4 a5 = *reinterpret_cast<const f32x4*>(ap + 20);
    f32x4 a6 = *reinterpret_cast<const f32x4*>(ap + 24);
    f32x4 a7 = *reinterpret_cast<const f32x4*>(ap + 28);
    f32x4 a8 = *reinterpret_cast<const f32x4*>(ap + 32);
    f32x4 a9 = *reinterpret_cast<const f32x4*>(ap + 36);
    f32x4 x0 = *reinterpret_cast<const f32x4*>(lg + 0 * kHW);
    f32x4 x1 = *reinterpret_cast<const f32x4*>(lg + 1 * kHW);
    f32x4 x2 = *reinterpret_cast<const f32x4*>(lg + 2 * kHW);
    f32x4 x3 = *reinterpret_cast<const f32x4*>(lg + 3 * kHW);
    f32x4 x4 = *reinterpret_cast<const f32x4*>(lg + 4 * kHW);
    f32x4 x5 = *reinterpret_cast<const f32x4*>(lg + 5 * kHW);
    f32x4 x6 = *reinterpret_cast<const f32x4*>(lg + 6 * kHW);
    f32x4 x7 = *reinterpret_cast<const f32x4*>(lg + 7 * kHW);
    f32x4 x8 = *reinterpret_cast<const f32x4*>(lg + 8 * kHW);
    f32x4 x9 = *reinterpret_cast<const f32x4*>(lg + 9 * kHW);

    // ---- FORCE materialization: all 21 results must be live VGPRs here.
    //      Loads cluster back-to-back -> one vmcnt drain, ~21 in flight. ----
    asm volatile("" : "+v"(tv),
                      "+v"(a0), "+v"(a1), "+v"(a2), "+v"(a3), "+v"(a4),
                      "+v"(a5), "+v"(a6), "+v"(a7), "+v"(a8), "+v"(a9),
                      "+v"(x0), "+v"(x1), "+v"(x2), "+v"(x3), "+v"(x4),
                      "+v"(x5), "+v"(x6), "+v"(x7), "+v"(x8), "+v"(x9));

    const int ta[4] = {tv[0], tv[1], tv[2], tv[3]};

    // ---- att: sum of squares + a_t select (frees a0..a9) ----
    float sq_acc = 0.f;
    float atq[4] = {0.f, 0.f, 0.f, 0.f};
#define IRIS_ATT(u, au)                                                        \
    _Pragma("unroll")                                                          \
    for (int e2 = 0; e2 < 4; ++e2) {                                           \
        const int e = 4 * (u) + e2;                                            \
        const int jx = e / kC;                                                 \
        const int ch = e - jx * kC;                                            \
        sq_acc += au[e2] * au[e2];                                             \
        atq[jx] = (ch == ta[jx]) ? au[e2] : atq[jx];                           \
    }
    IRIS_ATT(0, a0) IRIS_ATT(1, a1) IRIS_ATT(2, a2) IRIS_ATT(3, a3)
    IRIS_ATT(4, a4) IRIS_ATT(5, a5) IRIS_ATT(6, a6) IRIS_ATT(7, a7)
    IRIS_ATT(8, a8) IRIS_ATT(9, a9)
#undef IRIS_ATT
    float at_acc = atq[0] + atq[1] + atq[2] + atq[3];

    // ---- logits: two-pass softmax + argmax on resident registers ----
    float m[4] = {x0[0], x0[1], x0[2], x0[3]};
    float xt[4];
    int am[4] = {0, 0, 0, 0};
#pragma unroll
    for (int j = 0; j < 4; ++j) xt[j] = (ta[j] == 0) ? x0[j] : 0.f;
#define IRIS_P1(c, xc)                                                         \
    _Pragma("unroll")                                                          \
    for (int j = 0; j < 4; ++j) {                                              \
        const bool gt = xc[j] > m[j];          /* strict >: first max (JAX) */ \
        am[j] = gt ? (c) : am[j];                                              \
        m[j] = gt ? xc[j] : m[j];                                              \
        xt[j] = ((c) == ta[j]) ? xc[j] : xt[j];                                \
    }
    IRIS_P1(1, x1) IRIS_P1(2, x2) IRIS_P1(3, x3) IRIS_P1(4, x4)
    IRIS_P1(5, x5) IRIS_P1(6, x6) IRIS_P1(7, x7) IRIS_P1(8, x8)
    IRIS_P1(9, x9)
#undef IRIS_P1
    float s[4] = {0.f, 0.f, 0.f, 0.f};
#define IRIS_P2(xc)                                                            \
    _Pragma("unroll")                                                          \
    for (int j = 0; j < 4; ++j) s[j] += __expf(xc[j] - m[j]);
    IRIS_P2(x0) IRIS_P2(x1) IRIS_P2(x2) IRIS_P2(x3) IRIS_P2(x4)
    IRIS_P2(x5) IRIS_P2(x6) IRIS_P2(x7) IRIS_P2(x8) IRIS_P2(x9)
#undef IRIS_P2

    float ce_acc = 0.f;
    unsigned weq_acc = 0u, eq_acc = 0u;
#pragma unroll
    for (int j = 0; j < 4; ++j) {
        ce_acc += m[j] + __logf(s[j]) - xt[j];
        const unsigned eq = (am[j] == ta[j]) ? 1u : 0u;
        eq_acc += eq;
        const int p = p0 + j;
        const int h = p / kW;
        const int w = p - h * kW;
        weq_acc += eq * (((h == 0 || h == kH - 1) ? 1u : 2u) *
                         ((w == 0 || w == kW - 1) ? 1u : 2u));
    }

    // ---- wave + block reduce ----
#pragma unroll
    for (int off = 32; off > 0; off >>= 1) {
        ce_acc  += __shfl_down(ce_acc, off);
        at_acc  += __shfl_down(at_acc, off);
        sq_acc  += __shfl_down(sq_acc, off);
        weq_acc += __shfl_down(weq_acc, off);
        eq_acc  += __shfl_down(eq_acc, off);
    }
    __shared__ float sf[3][4];
    __shared__ unsigned su[2][4];
    const int wave = tid >> 6;
    if ((tid & 63) == 0) {
        sf[0][wave] = ce_acc; sf[1][wave] = at_acc; sf[2][wave] = sq_acc;
        su[0][wave] = weq_acc; su[1][wave] = eq_acc;
    }
    __syncthreads();
    if (tid == 0) {
        ce_part[blockIdx.x]   = sf[0][0] + sf[0][1] + sf[0][2] + sf[0][3];
        cmat_part[blockIdx.x] = sf[1][0] + sf[1][1] + sf[1][2] + sf[1][3];
        cmsq_part[blockIdx.x] = sf[2][0] + sf[2][1] + sf[2][2] + sf[2][3];
        weq_part[blockIdx.x]  = su[0][0] + su[0][1] + su[0][2] + su[0][3];
        eq_part[blockIdx.x]   = su[1][0] + su[1][1] + su[1][2] + su[1][3];
    }
}

// ---------- K-rules: one wave per batch (targets L3-warm re-read) ----------
__global__ __launch_bounds__(64) void iris_rules(
    const int* __restrict__ targets_g, const float* __restrict__ rules_g,
    float* __restrict__ rule_part) {
    const int b = blockIdx.x;
    const int lane = threadIdx.x;
    const int* __restrict__ tgt = targets_g + (size_t)b * kHW;
    unsigned mask = 0u;
    for (int k = lane; k < kHW; k += 64) mask |= 1u << tgt[k];  // coalesced
#pragma unroll
    for (int off = 32; off > 0; off >>= 1) mask |= __shfl_down(mask, off);
    if (lane == 0) {
        const float* __restrict__ lr = rules_g + (size_t)b * kC;
        unsigned mrem = mask;
        float rl = 0.f;
#pragma unroll
        for (int s2 = 0; s2 < kC; ++s2) {
            float v = 0.f;
            if (mrem) {
                v = (float)(__ffs(mrem) - 1);   // s-th smallest present color
                mrem &= mrem - 1u;
            }
            const float d = lr[s2] - v;
            rl += d * d;
        }
        rule_part[b] = rl;
    }
}

// ---------- K-final: deterministic double reduce ----------
__global__ __launch_bounds__(1024) void iris_finalize(
    const float* __restrict__ ce_part,
    const float* __restrict__ cmat_part,
    const float* __restrict__ cmsq_part,
    const unsigned* __restrict__ weq_part,
    const unsigned* __restrict__ eq_part,
    const float* __restrict__ rule_part,
    float* __restrict__ out) {
    const int tid = threadIdx.x;
    double ce = 0.0, cma = 0.0, cms = 0.0, rl = 0.0;
    unsigned long long weq = 0ull, eqc = 0ull;
    for (int i = tid; i < kGrid; i += 1024) {
        ce  += (double)ce_part[i];
        cma += (double)cmat_part[i];
        cms += (double)cmsq_part[i];
        weq += (unsigned long long)weq_part[i];
        eqc += (unsigned long long)eq_part[i];
    }
#pragma unroll
    for (int k = 0; k < 4; ++k) rl += (double)rule_part[tid + 1024 * k];
#pragma unroll
    for (int off = 32; off > 0; off >>= 1) {
        ce  += __shfl_down(ce, off);
        cma += __shfl_down(cma, off);
        cms += __shfl_down(cms, off);
        rl  += __shfl_down(rl, off);
        weq += __shfl_down(weq, off);
        eqc += __shfl_down(eqc, off);
    }
    __shared__ double sd[4][16];
    __shared__ unsigned long long su[2][16];
    const int wave = tid >> 6;
    if ((tid & 63) == 0) {
        sd[0][wave] = ce; sd[1][wave] = cma; sd[2][wave] = cms; sd[3][wave] = rl;
        su[0][wave] = weq; su[1][wave] = eqc;
    }
    __syncthreads();
    if (tid == 0) {
        ce = 0.0; cma = 0.0; cms = 0.0; rl = 0.0; weq = 0ull; eqc = 0ull;
#pragma unroll
        for (int i = 0; i < 16; ++i) {
            ce += sd[0][i]; cma += sd[1][i]; cms += sd[2][i]; rl += sd[3][i];
            weq += su[0][i]; eqc += su[1][i];
        }
        const double npix = (double)kB * kHW;
        const double ce_m = ce / npix;
        const double cm_m = (cms - 2.0 * cma + npix) / (npix * kC);
        const double s_mean = (double)weq / ((double)kB * (kH - 1) * (kW - 1));
        const double cons = 1.0 - s_mean / 4.0;
        const double rl_m = rl / ((double)kB * kC);
        const double exact = (double)eqc;
        double total = ce_m + 0.4 * cm_m + 0.3 * cons + 0.2 * rl_m
                       - (exact / (double)kB) * 5.0;
        if (total < 0.001) total = 0.001;
        out[0] = (float)total;
        out[1] = (float)ce_m;
        out[2] = (float)cm_m;
        out[3] = (float)cons;
        out[4] = (float)rl_m;
        out[5] = (float)exact;
    }
}

extern "C" void kernel_launch(void* const* d_in, const int* in_sizes, int n_in,
                              void* d_out, int out_size, void* d_ws, size_t ws_size,
                              hipStream_t stream) {
    const float* color_output    = (const float*)d_in[0];
    const int*   targets         = (const int*)d_in[1];
    const float* color_attention = (const float*)d_in[2];
    const float* lstm_rules      = (const float*)d_in[3];
    float* out = (float*)d_out;

    // workspace: 5 x kGrid (3600) + kB rules = 88,384 B
    float*    ce_part   = (float*)d_ws;
    float*    cmat_part = ce_part + kGrid;
    float*    cmsq_part = cmat_part + kGrid;
    unsigned* weq_part  = (unsigned*)(cmsq_part + kGrid);
    unsigned* eq_part   = weq_part + kGrid;
    float*    rule_part = (float*)(eq_part + kGrid);

    iris_fused<<<kGrid, kThreads, 0, stream>>>(color_output, targets,
                                               color_attention, ce_part,
                                               cmat_part, cmsq_part,
                                               weq_part, eq_part);
    iris_rules<<<kB, 64, 0, stream>>>(targets, lstm_rules, rule_part);
    iris_finalize<<<1, 1024, 0, stream>>>(ce_part, cmat_part, cmsq_part,
                                          weq_part, eq_part, rule_part, out);
}